// Round 4
// baseline (192.034 us; speedup 1.0000x reference)
//
#include <hip/hip_runtime.h>
#include <hip/hip_bf16.h>

#define N_Q 256
#define M_S 1024
#define DD 512
#define HH 512

typedef __attribute__((ext_vector_type(8))) short short8;
typedef __attribute__((ext_vector_type(8))) __bf16 bf16x8;
typedef __attribute__((ext_vector_type(16))) float f32x16;
typedef __attribute__((ext_vector_type(2))) __bf16 bf16x2;

union U8 { short8 s; bf16x8 b; };

__device__ __forceinline__ unsigned short f2bf(float f) {
  unsigned int u = __float_as_uint(f);
  u += 0x7FFFu + ((u >> 16) & 1u);
  return (unsigned short)(u >> 16);
}

__device__ __forceinline__ short8 pack8(const float* d) {
#if defined(__has_builtin) && __has_builtin(__builtin_amdgcn_cvt_pk_bf16_f32)
  short8 r;
#pragma unroll
  for (int i = 0; i < 4; ++i) {
    union { bf16x2 v; short s[2]; } u;
    u.v = __builtin_amdgcn_cvt_pk_bf16_f32(d[2 * i], d[2 * i + 1]);
    r[2 * i] = u.s[0];
    r[2 * i + 1] = u.s[1];
  }
  return r;
#else
  short8 r;
#pragma unroll
  for (int i = 0; i < 8; ++i) r[i] = (short)f2bf(d[i]);
  return r;
#endif
}

__device__ __forceinline__ short8 packdiff(float4 e0, float4 e1, float4 s0, float4 s1) {
  float d[8];
  d[0] = fabsf(e0.x - s0.x); d[1] = fabsf(e0.y - s0.y);
  d[2] = fabsf(e0.z - s0.z); d[3] = fabsf(e0.w - s0.w);
  d[4] = fabsf(e1.x - s1.x); d[5] = fabsf(e1.y - s1.y);
  d[6] = fabsf(e1.z - s1.z); d[7] = fabsf(e1.w - s1.w);
  return pack8(d);
}

// W1 [D][H] fp32 -> w1s in MFMA-fragment order.
// Fragment map (verified): w1s[f*512 + l*8 + j] = W1[k][h] with
//   f = (k>>4)*16 + (h>>5), l = ((k>>3)&1)*32 + (h&31), j = k&7.
// Coalesced rewrite: 65536 threads, float4 read (4 h per thread), 4 stores.
__global__ __launch_bounds__(1024) void prep_w1s(const float* __restrict__ W1,
                                                 unsigned short* __restrict__ w1s) {
  const int gid = blockIdx.x * 1024 + threadIdx.x;  // 0..65535
  const int k = gid >> 7;                            // 0..511
  const int hq = gid & 127;                          // h-quad
  const float4 w = *(const float4*)(W1 + k * HH + hq * 4);
  const int f = (k >> 4) * 16 + (hq >> 3);
  const int lk = ((k >> 3) & 1) * 32 + (hq & 7) * 4; // l base for i=0
  const int j = k & 7;
  unsigned short* p = w1s + f * 512 + lk * 8 + j;    // stride 8 shorts per h
  p[0]  = f2bf(w.x);
  p[8]  = f2bf(w.y);
  p[16] = f2bf(w.z);
  p[24] = f2bf(w.w);
}

// Block: 512 thr = 8 waves. Tile 128 pairs (8 emb x 16 sup) x 512 h x K=512.
// A (diff) staged ONCE into 128 KB LDS, layout [p][c ^ (p&7)] in 16B chunks.
// Wave wid = hslice (64 h); every wave covers all 128 pairs (acc[4][2]).
// MFMA operand-swapped: A-op = W1^T frag (regs, L2), B-op = diff frag (LDS);
// C col = pair, row = h => in-lane h-reduce epilogue.
// K-loop ordering: MFMA cluster FIRST, then prefetch loads (A depth 2 ring-3,
// W1 depth 3 ring-4) — every cluster input is >=1 full iteration old, so
// conservative waitcnt drains cost ~0 (theory: R3's 55% stall was per-iter
// latency exposure from loads issued just before the cluster).
// ~235 regs -> 2 waves/SIMD; psums in dedicated LDS (no aliasing barrier).
__global__ __launch_bounds__(512, 2) void support_kernel(
    const float* __restrict__ emb, const float* __restrict__ sup,
    const unsigned short* __restrict__ w1s, const float* __restrict__ b1,
    const float* __restrict__ W2, const float* __restrict__ b2,
    float* __restrict__ out) {
  extern __shared__ short8 As16[];   // [128][64] = 131072 B + psums 4608 B

  const int tid = threadIdx.x;
  const int lane = tid & 63;
  const int wid = tid >> 6;          // 0..7 = hslice (h base = wid*64)
  const int l31 = lane & 31;
  const int khalf = lane >> 5;

  const int m0 = blockIdx.x * 16;
  const int n0 = blockIdx.y * 8;

  // ---- W1-frag prologue: depth-3 (ks=0,1,2), issued BEFORE staging ----
  const unsigned short* bb = w1s + (wid * 2) * 512 + lane * 8;
  U8 b[4][2];
#pragma unroll
  for (int s = 0; s < 3; ++s)
#pragma unroll
    for (int tj = 0; tj < 2; ++tj)
      b[s][tj].s = *(const short8*)(bb + (s * 16 + tj) * 512);

  // ---- stage 128p x 512k diffs (once): thread = (emb row rg, k-chunk c) ----
  {
    const int c = tid & 63;
    const int rg = tid >> 6;           // emb row 0..7
    const float* ep = emb + (n0 + rg) * DD + c * 8;
    const float4 e0 = *(const float4*)ep;
    const float4 e1 = *(const float4*)(ep + 4);
    const float* sbase = sup + m0 * DD + c * 8;
#pragma unroll
    for (int j = 0; j < 16; ++j) {     // 16 sup rows
      const float4 s0 = *(const float4*)(sbase + j * DD);
      const float4 s1 = *(const float4*)(sbase + j * DD + 4);
      const int p = rg * 16 + j;       // p&7 == j&7
      As16[p * 64 + (c ^ (j & 7))] = packdiff(e0, e1, s0, s1);
    }
  }
  __syncthreads();  // barrier 1: tile visible

  // ---- K-loop: 32 steps of 16 k, 8 MFMA each; loads trail the cluster ----
  const int ax = l31 & 7;            // read-side chunk XOR (row&7 == l31&7)
  const int ar0 = (0 * 32 + l31) * 64;
  const int ar1 = (1 * 32 + l31) * 64;
  const int ar2 = (2 * 32 + l31) * 64;
  const int ar3 = (3 * 32 + l31) * 64;

  f32x16 acc[4][2] = {};
  U8 a[3][4];
#pragma unroll
  for (int s = 0; s < 2; ++s) {      // A prologue: ks=0,1
    const int c = (s * 2 + khalf) ^ ax;
    a[s][0].s = As16[ar0 + c];
    a[s][1].s = As16[ar1 + c];
    a[s][2].s = As16[ar2 + c];
    a[s][3].s = As16[ar3 + c];
  }

#pragma unroll
  for (int ks = 0; ks < 32; ++ks) {
    __builtin_amdgcn_s_setprio(1);
#pragma unroll
    for (int am = 0; am < 4; ++am)
#pragma unroll
      for (int tj = 0; tj < 2; ++tj)
        acc[am][tj] = __builtin_amdgcn_mfma_f32_32x32x16_bf16(
            b[ks & 3][tj].b, a[ks % 3][am].b, acc[am][tj], 0, 0, 0);
    __builtin_amdgcn_s_setprio(0);
    if (ks + 2 < 32) {  // A-frag prefetch, depth 2 (LDS)
      const int cc = ((ks + 2) * 2 + khalf) ^ ax;
      const int slot = (ks + 2) % 3;
      a[slot][0].s = As16[ar0 + cc];
      a[slot][1].s = As16[ar1 + cc];
      a[slot][2].s = As16[ar2 + cc];
      a[slot][3].s = As16[ar3 + cc];
    }
    if (ks + 3 < 32) {  // W1-frag prefetch, depth 3 (L2)
#pragma unroll
      for (int tj = 0; tj < 2; ++tj)
        b[(ks + 3) & 3][tj].s = *(const short8*)(bb + ((ks + 3) * 16 + tj) * 512);
    }
  }

  // ---- epilogue: C col = pair (l31 + am*32), row = h: (r&3)+8*(r>>2)+4*khalf
  // In-lane reduce over 64 h per wave; one xor-32 shuffle per am.
  float s0a, s1a, s2a, s3a;
  {
    float sm[4] = {0.f, 0.f, 0.f, 0.f};
#pragma unroll
    for (int tj = 0; tj < 2; ++tj) {
      const float* b1p = b1 + (wid * 2 + tj) * 32 + khalf * 4;
      const float* w2p = W2 + (wid * 2 + tj) * 32 + khalf * 4;
#pragma unroll
      for (int rq = 0; rq < 4; ++rq) {
        const float4 b1q = *(const float4*)(b1p + rq * 8);
        const float4 w2q = *(const float4*)(w2p + rq * 8);
#pragma unroll
        for (int am = 0; am < 4; ++am) {
          sm[am] += fmaxf(acc[am][tj][rq * 4 + 0] + b1q.x, 0.f) * w2q.x;
          sm[am] += fmaxf(acc[am][tj][rq * 4 + 1] + b1q.y, 0.f) * w2q.y;
          sm[am] += fmaxf(acc[am][tj][rq * 4 + 2] + b1q.z, 0.f) * w2q.z;
          sm[am] += fmaxf(acc[am][tj][rq * 4 + 3] + b1q.w, 0.f) * w2q.w;
        }
      }
    }
#pragma unroll
    for (int am = 0; am < 4; ++am) sm[am] += __shfl_xor(sm[am], 32, 64);
    s0a = sm[0]; s1a = sm[1]; s2a = sm[2]; s3a = sm[3];
  }
  // psums in dedicated region beyond the A tile — no aliasing barrier needed
  float* psums = (float*)(As16 + 128 * 64);  // [128 pairs][9]
  {
    const float v0 = khalf ? s2a : s0a;
    const float v1 = khalf ? s3a : s1a;
    const int p0 = khalf * 64 + l31;       // am = khalf*2     -> pair base
    psums[p0 * 9 + wid] = v0;
    psums[(p0 + 32) * 9 + wid] = v1;       // am = khalf*2 + 1
  }
  __syncthreads();  // barrier 2 (final): psums visible
  if (tid < 128) {
    float t = b2[0];
#pragma unroll
    for (int w = 0; w < 8; ++w) t += psums[tid * 9 + w];
    out[(n0 + (tid >> 4)) * M_S + m0 + (tid & 15)] = 1.f / (1.f + __expf(-t));
  }
}

extern "C" void kernel_launch(void* const* d_in, const int* in_sizes, int n_in,
                              void* d_out, int out_size, void* d_ws, size_t ws_size,
                              hipStream_t stream) {
  const float* emb = (const float*)d_in[0];
  const float* sup = (const float*)d_in[1];
  const float* W1  = (const float*)d_in[2];
  const float* b1  = (const float*)d_in[3];
  const float* W2  = (const float*)d_in[4];
  const float* b2  = (const float*)d_in[5];
  float* out = (float*)d_out;
  unsigned short* w1s = (unsigned short*)d_ws;  // 512 KB fragment-ordered W1

  static bool attr_done = false;
  if (!attr_done) {
    hipFuncSetAttribute((const void*)support_kernel,
                        hipFuncAttributeMaxDynamicSharedMemorySize, 135680);
    attr_done = true;
  }

  prep_w1s<<<64, 1024, 0, stream>>>(W1, w1s);
  support_kernel<<<dim3(M_S / 16, N_Q / 8), 512, 135680, stream>>>(
      emb, sup, w1s, b1, W2, b2, out);
}